// Round 4
// baseline (1304.349 us; speedup 1.0000x reference)
//
#include <hip/hip_runtime.h>
#include <cstdint>

#define NTHREADS 512
#define L_SEQ 2048
#define D_DIM 1024
#define BQ 64
#define BK 32          // Vt tile granularity (layout unchanged)
#define BK2 64         // keys processed per main-loop iteration (2 Vt tiles)
#define NKT (L_SEQ / BK)   // 64 key tiles (Vt layout)
#define NQT (L_SEQ / BQ)   // 32 query tiles

// ---- fallback (original) kernel LDS layout ----
#define KST 1032
#define VST 34
#define SST 36
#define PST 40
#define K_OFF 0
#define K_BYTES (BK * KST * 2)
#define V_OFF (K_OFF + K_BYTES)
#define V_BYTES (D_DIM * VST * 2)
#define S_OFF (V_OFF + V_BYTES)
#define S_BYTES (BQ * SST * 4)
#define P_OFF (S_OFF + S_BYTES)
#define P_BYTES (BQ * PST * 2)
#define M_OFF (P_OFF + P_BYTES)
#define LDS_TOTAL (M_OFF + BQ * 4 * 3 + 16)

typedef unsigned int u32;
typedef __bf16 bf16x8 __attribute__((ext_vector_type(8)));
typedef float f32x4 __attribute__((ext_vector_type(4)));

// nt-load helper: __builtin_nontemporal_load rejects HIP_vector_type pointers,
// but accepts clang ext_vector_type.
__device__ __forceinline__ f32x4 ntload4(const float* p) {
  return __builtin_nontemporal_load((const f32x4*)p);
}

__device__ __forceinline__ f32x4 mfma16(int4 a, int4 b, f32x4 c) {
  return __builtin_amdgcn_mfma_f32_16x16x32_bf16(
      __builtin_bit_cast(bf16x8, a), __builtin_bit_cast(bf16x8, b), c, 0, 0, 0);
}

// pack two fp32 -> bf16x2 (same rounding as previous verified kernel)
__device__ __forceinline__ u32 pk2(float a, float b) {
  u32 ua = __float_as_uint(a) + 0x8000u;
  u32 ub = __float_as_uint(b) + 0x8000u;
  return (ua >> 16) | (ub & 0xffff0000u);
}

#define SFIX 4096.0f

// ================= prologue: K -> bf16 (same layout), V -> bf16 tile-transposed =================
// Vt layout: [b][kt32][d][32 keys] bf16, each tile a contiguous 64KB chunk.
// All 16 V float4 preloaded to regs BEFORE the barrier-separated chunk phases so
// nt-load latency is paid once, not 4x between barriers.
#define CVT_PAD 257   // 257 % 32 == 1 -> transpose-gather reads are 2-way (free)

__global__ __launch_bounds__(512)
void cvt_kv(const float* __restrict__ Kg, const float* __restrict__ Vg,
            unsigned short* __restrict__ Kb16, unsigned short* __restrict__ Vt) {
  __shared__ float vls[32 * CVT_PAD];   // 32.9 KB
  const int tid = threadIdx.x;
  const int kt = blockIdx.x;
  const int b = blockIdx.y;
  const size_t inbase = ((size_t)b * L_SEQ + (size_t)kt * BK) * D_DIM;

  // K tile convert: 32x1024 fp32 -> bf16, flat coalesced, nt reads
  {
    const float* Ks = Kg + inbase;
    uint2* Ko = (uint2*)(Kb16 + inbase);
#pragma unroll
    for (int i = 0; i < 16; ++i) {
      f32x4 x = ntload4(Ks + (size_t)(i * 512 + tid) * 4);
      Ko[i * 512 + tid] = make_uint2(pk2(x[0], x[1]), pk2(x[2], x[3]));
    }
  }
  // V: preload ALL chunks into registers (16 f32x4), then barriered transpose phases
  const float* Vsf = Vg + inbase;
  f32x4 vr[16];
#pragma unroll
  for (int i = 0; i < 16; ++i) {
    int u = (i & 3) * 512 + tid;       // within-chunk flat index
    int c = i >> 2;                     // chunk 0..3
    int row = u >> 6;                   // key 0..31
    int col4 = u & 63;                  // float4 within 256-d chunk
    vr[i] = ntload4(Vsf + (size_t)row * D_DIM + c * 256 + col4 * 4);
  }
  int4* Vo = (int4*)(Vt + ((size_t)b * NKT + kt) * (size_t)(D_DIM * BK));
#pragma unroll
  for (int c = 0; c < 4; ++c) {
    __syncthreads();   // previous chunk's readers done
#pragma unroll
    for (int i = 0; i < 4; ++i) {
      int u = i * 512 + tid;
      int row = u >> 6;
      int col4 = u & 63;
      *(f32x4*)&vls[row * CVT_PAD + col4 * 4] = vr[c * 4 + i];
    }
    __syncthreads();
#pragma unroll
    for (int i = 0; i < 2; ++i) {
      int o4 = i * 512 + tid;          // 0..1023
      int d = o4 >> 2;                 // 0..255 (chunk-local)
      int k0 = (o4 & 3) * 8;           // key start for this int4 (8 keys)
      u32 w0 = pk2(vls[(k0 + 0) * CVT_PAD + d], vls[(k0 + 1) * CVT_PAD + d]);
      u32 w1 = pk2(vls[(k0 + 2) * CVT_PAD + d], vls[(k0 + 3) * CVT_PAD + d]);
      u32 w2 = pk2(vls[(k0 + 4) * CVT_PAD + d], vls[(k0 + 5) * CVT_PAD + d]);
      u32 w3 = pk2(vls[(k0 + 6) * CVT_PAD + d], vls[(k0 + 7) * CVT_PAD + d]);
      Vo[(c * 256 + d) * 4 + (o4 & 3)] = make_int4((int)w0, (int)w1, (int)w2, (int)w3);
    }
  }
}

// ================= main kernel: BK2=64 per iteration, defer-max, setprio =================
__global__ __attribute__((amdgpu_waves_per_eu(2, 2))) __launch_bounds__(NTHREADS)
void fa_fwd_pre(const float* __restrict__ Qg, const unsigned short* __restrict__ Kb16,
                const unsigned short* __restrict__ Vt, float* __restrict__ Og, int B) {
  __shared__ int Ssh[2][BQ * SST];              // fixed-point partial scores, per 32-key half
  __shared__ unsigned short Psh[2][BQ * PST];   // bf16 probs, per 32-key half
  __shared__ float msh[BQ], lsh[BQ], ash[BQ];   // running max / denom / alpha
  __shared__ int fsh[2][4];                     // double-buffered rescale flags

  const int tid = threadIdx.x;
  const int lane = tid & 63;
  const int wave = tid >> 6;         // d-slice owner: cols [wave*128, wave*128+128)
  const int r = lane & 15;
  const int quad = lane >> 4;

  // XCD-co-scheduled mapping (see R3 notes): all 32 CUs of an XCD on one batch.
  const int f = (int)blockIdx.y * (int)gridDim.x + (int)blockIdx.x;
  int b, qtile;
  if ((B & 7) == 0) {
    int xcd = f & 7;
    int s = f >> 3;                   // per-XCD slot
    b = (s >> 5) * 8 + xcd;          // round * 8 + xcd   (NQT == 32)
    qtile = (NQT - 1) - (s & (NQT - 1));
  } else {
    b = f % B;
    qtile = (int)gridDim.x - 1 - (f / B);
  }
  const int q0 = qtile * BQ;
  const size_t base = (size_t)b * L_SEQ * D_DIM;
  const float* Qb = Qg + base;
  const unsigned short* Kbb = Kb16 + base;
  const unsigned short* Vtb = Vt + (size_t)b * NKT * (size_t)(D_DIM * BK);
  float* Ob = Og + base;

  // ---- Q fragments, bf16, persistent (nt loads: Q touched exactly once) ----
  int4 qf[4][4];
#pragma unroll
  for (int m = 0; m < 4; ++m)
#pragma unroll
    for (int ks = 0; ks < 4; ++ks) {
      const float* src = Qb + (size_t)(q0 + m * 16 + r) * D_DIM + wave * 128 + ks * 32 + quad * 8;
      f32x4 x = ntload4(src);
      f32x4 y = ntload4(src + 4);
      qf[m][ks] = make_int4((int)pk2(x[0], x[1]), (int)pk2(x[2], x[3]),
                            (int)pk2(y[0], y[1]), (int)pk2(y[2], y[3]));
    }

  f32x4 o[4][8];
  const f32x4 fzero = {0.f, 0.f, 0.f, 0.f};
#pragma unroll
  for (int m = 0; m < 4; ++m)
#pragma unroll
    for (int n = 0; n < 8; ++n) o[m][n] = fzero;

  if (tid < BQ) { msh[tid] = -3.0e38f; lsh[tid] = 0.f; }
  if (tid < 8) fsh[tid >> 2][tid & 3] = 0;
  {  // zero both score halves once; thereafter softmax re-zeros its own int4s
    int q = tid >> 3, k4 = (tid & 7) * 4;
    *(int4*)&Ssh[0][q * SST + k4] = make_int4(0, 0, 0, 0);
    *(int4*)&Ssh[1][q * SST + k4] = make_int4(0, 0, 0, 0);
  }
  __syncthreads();

  const int nkt2 = qtile + 1;                  // 64-key iterations (causal)
  const float SC = 0.04508422002778011f;       // log2(e) / sqrt(1024)
  const float SCI = SC / SFIX;

  for (int kt2 = 0; kt2 < nkt2; ++kt2) {
    const int cur = kt2 & 1;
    const int k0 = kt2 * BK2;

    // ---- QK^T over 64 keys: direct global bf16 K fragments, LDS int atomics ----
#pragma unroll 1
    for (int h = 0; h < 2; ++h) {
#pragma unroll
      for (int nb = 0; nb < 2; ++nb) {
        f32x4 sp[4];
#pragma unroll
        for (int m = 0; m < 4; ++m) sp[m] = fzero;
        __builtin_amdgcn_s_setprio(1);
#pragma unroll
        for (int ks = 0; ks < 4; ++ks) {
          int4 kb = *(const int4*)(Kbb + (size_t)(k0 + h * 32 + nb * 16 + r) * D_DIM +
                                   wave * 128 + ks * 32 + quad * 8);
#pragma unroll
          for (int m = 0; m < 4; ++m) sp[m] = mfma16(qf[m][ks], kb, sp[m]);
        }
        __builtin_amdgcn_s_setprio(0);
#pragma unroll
        for (int m = 0; m < 4; ++m)
#pragma unroll
          for (int i = 0; i < 4; ++i) {
            int v = __float2int_rn(sp[m][i] * SFIX);
            atomicAdd(&Ssh[h][(m * 16 + quad * 4 + i) * SST + nb * 16 + r], v);
          }
      }
    }
    __syncthreads();  // (1) S complete; prev-iter P/ash consumers also done

    // ---- online softmax, 64 keys/row: 8 threads per row (8 keys each) ----
    {
      const int q = tid >> 3, t8 = tid & 7;
      const int h = t8 >> 2, c = (t8 & 3) * 8;
      int* srow = &Ssh[h][q * SST + c];
      int4 sv0 = *(int4*)srow;
      int4 sv1 = *(int4*)(srow + 4);
      *(int4*)srow = make_int4(0, 0, 0, 0);
      *(int4*)(srow + 4) = make_int4(0, 0, 0, 0);
      const int qglob = q0 + q;
      const int kb0 = k0 + h * 32 + c;
      float e0 = (kb0 + 0 <= qglob) ? (float)sv0.x * SCI : -1e30f;
      float e1 = (kb0 + 1 <= qglob) ? (float)sv0.y * SCI : -1e30f;
      float e2 = (kb0 + 2 <= qglob) ? (float)sv0.z * SCI : -1e30f;
      float e3 = (kb0 + 3 <= qglob) ? (float)sv0.w * SCI : -1e30f;
      float e4 = (kb0 + 4 <= qglob) ? (float)sv1.x * SCI : -1e30f;
      float e5 = (kb0 + 5 <= qglob) ? (float)sv1.y * SCI : -1e30f;
      float e6 = (kb0 + 6 <= qglob) ? (float)sv1.z * SCI : -1e30f;
      float e7 = (kb0 + 7 <= qglob) ? (float)sv1.w * SCI : -1e30f;
      float mx = fmaxf(fmaxf(fmaxf(e0, e1), fmaxf(e2, e3)),
                       fmaxf(fmaxf(e4, e5), fmaxf(e6, e7)));
      mx = fmaxf(mx, __shfl_xor(mx, 1));
      mx = fmaxf(mx, __shfl_xor(mx, 2));
      mx = fmaxf(mx, __shfl_xor(mx, 4));
      float mprev = msh[q], lprev = lsh[q];
      // T13 defer-max: only rescale when the max grew by >8 (log2 domain).
      // P is then bounded by 2^8=256 — fine in bf16/f32.
      bool resc = (mx - mprev) > 8.0f;
      float mused = resc ? mx : mprev;
      float alpha = resc ? exp2f(mprev - mx) : 1.0f;
      float p0 = exp2f(e0 - mused), p1 = exp2f(e1 - mused);
      float p2 = exp2f(e2 - mused), p3 = exp2f(e3 - mused);
      float p4 = exp2f(e4 - mused), p5 = exp2f(e5 - mused);
      float p6 = exp2f(e6 - mused), p7 = exp2f(e7 - mused);
      float sum = ((p0 + p1) + (p2 + p3)) + ((p4 + p5) + (p6 + p7));
      sum += __shfl_xor(sum, 1);
      sum += __shfl_xor(sum, 2);
      sum += __shfl_xor(sum, 4);
      *(int4*)&Psh[h][q * PST + c] =
          make_int4((int)pk2(p0, p1), (int)pk2(p2, p3), (int)pk2(p4, p5), (int)pk2(p6, p7));
      if (t8 == 0) {
        msh[q] = mused;
        lsh[q] = lprev * alpha + sum;
        ash[q] = alpha;
        if (resc) fsh[cur][q >> 4] = 1;  // same-value racy store: fine
      }
      if (tid < 4) fsh[cur ^ 1][tid] = 0;  // reset next iter's flags
    }
    __syncthreads();  // (2) P/alpha/flags ready

    // ---- rare O rescale + PV over both 32-key halves ----
    {
#pragma unroll
      for (int m = 0; m < 4; ++m) {
        if (fsh[cur][m]) {  // wave-uniform; rare with defer-max
          float a0 = ash[m * 16 + quad * 4 + 0];
          float a1 = ash[m * 16 + quad * 4 + 1];
          float a2 = ash[m * 16 + quad * 4 + 2];
          float a3 = ash[m * 16 + quad * 4 + 3];
#pragma unroll
          for (int n = 0; n < 8; ++n) {
            o[m][n][0] *= a0; o[m][n][1] *= a1; o[m][n][2] *= a2; o[m][n][3] *= a3;
          }
        }
      }
      int4 pf[4][2];
#pragma unroll
      for (int m = 0; m < 4; ++m)
#pragma unroll
        for (int h = 0; h < 2; ++h)
          pf[m][h] = *(int4*)&Psh[h][(m * 16 + r) * PST + quad * 8];
      const unsigned short* Vt0 = Vtb + (size_t)(kt2 * 2) * (D_DIM * BK);
#pragma unroll 2
      for (int n = 0; n < 8; ++n) {
        __builtin_amdgcn_s_setprio(1);
#pragma unroll
        for (int h = 0; h < 2; ++h) {
          int4 vb = *(const int4*)(Vt0 + (size_t)h * (D_DIM * BK) +
                                   (wave * 128 + n * 16 + r) * BK + quad * 8);
#pragma unroll
          for (int m = 0; m < 4; ++m) o[m][n] = mfma16(pf[m][h], vb, o[m][n]);
        }
        __builtin_amdgcn_s_setprio(0);
      }
    }
  }

  // ---- epilogue: O / l (nt stores: O never re-read) ----
#pragma unroll
  for (int m = 0; m < 4; ++m) {
    float inv0 = 1.0f / lsh[m * 16 + quad * 4 + 0];
    float inv1 = 1.0f / lsh[m * 16 + quad * 4 + 1];
    float inv2 = 1.0f / lsh[m * 16 + quad * 4 + 2];
    float inv3 = 1.0f / lsh[m * 16 + quad * 4 + 3];
#pragma unroll
    for (int n = 0; n < 8; ++n) {
      size_t row = (size_t)q0 + m * 16 + quad * 4;
      size_t col = (size_t)wave * 128 + n * 16 + r;
      __builtin_nontemporal_store(o[m][n][0] * inv0, &Ob[(row + 0) * D_DIM + col]);
      __builtin_nontemporal_store(o[m][n][1] * inv1, &Ob[(row + 1) * D_DIM + col]);
      __builtin_nontemporal_store(o[m][n][2] * inv2, &Ob[(row + 2) * D_DIM + col]);
      __builtin_nontemporal_store(o[m][n][3] * inv3, &Ob[(row + 3) * D_DIM + col]);
    }
  }
}

// ================= fallback: previous verified kernel (used if workspace too small) =================
__global__ __attribute__((amdgpu_waves_per_eu(2, 2))) __launch_bounds__(NTHREADS)
void fa_fwd(const float* __restrict__ Qg, const float* __restrict__ Kg,
            const float* __restrict__ Vg, float* __restrict__ Og) {
  extern __shared__ char smem[];
  unsigned short* Ksh = (unsigned short*)(smem + K_OFF);
  unsigned short* Vtsh = (unsigned short*)(smem + V_OFF);
  int* Ssh = (int*)(smem + S_OFF);
  unsigned short* Psh = (unsigned short*)(smem + P_OFF);
  float* msh = (float*)(smem + M_OFF);
  float* lsh = msh + BQ;
  float* ash = lsh + BQ;
  int* fsh = (int*)(ash + BQ);

  const int tid = threadIdx.x;
  const int lane = tid & 63;
  const int wave = tid >> 6;
  const int r = lane & 15;
  const int quad = lane >> 4;

  const int qtile = (int)gridDim.x - 1 - (int)blockIdx.x;
  const int q0 = qtile * BQ;
  const int b = blockIdx.y;
  const size_t base = (size_t)b * L_SEQ * D_DIM;
  const float* Qb = Qg + base;
  const float* Kb = Kg + base;
  const float* Vb = Vg + base;
  float* Ob = Og + base;

  int4 qf[4][4];
#pragma unroll
  for (int m = 0; m < 4; ++m)
#pragma unroll
    for (int ks = 0; ks < 4; ++ks) {
      const float* src = Qb + (size_t)(q0 + m * 16 + r) * D_DIM + wave * 128 + ks * 32 + quad * 8;
      float4 x = *(const float4*)src;
      float4 y = *(const float4*)(src + 4);
      qf[m][ks] = make_int4((int)pk2(x.x, x.y), (int)pk2(x.z, x.w),
                            (int)pk2(y.x, y.y), (int)pk2(y.z, y.w));
    }

  f32x4 o[4][8];
  const f32x4 fzero = {0.f, 0.f, 0.f, 0.f};
#pragma unroll
  for (int m = 0; m < 4; ++m)
#pragma unroll
    for (int n = 0; n < 8; ++n) o[m][n] = fzero;

  if (tid < BQ) { msh[tid] = -3.0e38f; lsh[tid] = 0.f; }

  const int nkt = q0 / BK + 2;
  const float SC = 0.04508422002778011f;
  const float SCI = SC / SFIX;

  for (int kt = 0; kt < nkt; ++kt) {
    __syncthreads();
    {
      const float* Ks = Kb + (size_t)kt * BK * D_DIM;
#pragma unroll 8
      for (int i = 0; i < 16; ++i) {
        int u = i * NTHREADS + tid;
        int key = u >> 8;
        int c = u & 255;
        float4 v = *(const float4*)(Ks + key * D_DIM + c * 4);
        *(uint2*)&Ksh[key * KST + c * 4] = make_uint2(pk2(v.x, v.y), pk2(v.z, v.w));
      }
      const float* Vs = Vb + (size_t)kt * BK * D_DIM;
#pragma unroll 8
      for (int i = 0; i < 32; ++i) {
        int u = i * NTHREADS + tid;
        int kp = u >> 10;
        int d = u & 1023;
        float a = Vs[kp * 2 * D_DIM + d];
        float c2 = Vs[(kp * 2 + 1) * D_DIM + d];
        *(u32*)&Vtsh[d * VST + kp * 2] = pk2(a, c2);
      }
      int q = tid >> 3, k4 = (tid & 7) * 4;
      *(int4*)&Ssh[q * SST + k4] = make_int4(0, 0, 0, 0);
      if (tid < 4) fsh[tid] = 0;
    }
    __syncthreads();

#pragma unroll
    for (int nb = 0; nb < 2; ++nb) {
      f32x4 sp[4];
#pragma unroll
      for (int m = 0; m < 4; ++m) sp[m] = fzero;
#pragma unroll
      for (int ks = 0; ks < 4; ++ks) {
        int dcol = wave * 128 + ks * 32 + quad * 8;
        int4 kb = *(int4*)&Ksh[(nb * 16 + r) * KST + dcol];
#pragma unroll
        for (int m = 0; m < 4; ++m) sp[m] = mfma16(qf[m][ks], kb, sp[m]);
      }
#pragma unroll
      for (int m = 0; m < 4; ++m)
#pragma unroll
        for (int i = 0; i < 4; ++i) {
          int v = __float2int_rn(sp[m][i] * SFIX);
          atomicAdd(&Ssh[(m * 16 + quad * 4 + i) * SST + nb * 16 + r], v);
        }
    }
    __syncthreads();

    {
      int q = tid >> 3, kk = (tid & 7) * 4;
      int4 sv = *(int4*)&Ssh[q * SST + kk];
      int qglob = q0 + q, kglob = kt * BK + kk;
      float e0 = (kglob <= qglob) ? (float)sv.x * SCI : -1e30f;
      float e1 = (kglob + 1 <= qglob) ? (float)sv.y * SCI : -1e30f;
      float e2 = (kglob + 2 <= qglob) ? (float)sv.z * SCI : -1e30f;
      float e3 = (kglob + 3 <= qglob) ? (float)sv.w * SCI : -1e30f;
      float mx = fmaxf(fmaxf(e0, e1), fmaxf(e2, e3));
      mx = fmaxf(mx, __shfl_xor(mx, 1));
      mx = fmaxf(mx, __shfl_xor(mx, 2));
      mx = fmaxf(mx, __shfl_xor(mx, 4));
      float mprev = msh[q], lprev = lsh[q];
      float mnew = fmaxf(mprev, mx);
      float alpha = exp2f(mprev - mnew);
      float p0 = exp2f(e0 - mnew), p1 = exp2f(e1 - mnew);
      float p2 = exp2f(e2 - mnew), p3 = exp2f(e3 - mnew);
      float sum = (p0 + p1) + (p2 + p3);
      sum += __shfl_xor(sum, 1);
      sum += __shfl_xor(sum, 2);
      sum += __shfl_xor(sum, 4);
      *(uint2*)&Psh[q * PST + kk] = make_uint2(pk2(p0, p1), pk2(p2, p3));
      if ((tid & 7) == 0) {
        msh[q] = mnew;
        lsh[q] = lprev * alpha + sum;
        ash[q] = alpha;
        if (alpha != 1.0f) fsh[q >> 4] = 1;
      }
    }
    __syncthreads();

    {
#pragma unroll
      for (int m = 0; m < 4; ++m) {
        if (fsh[m]) {
          float a0 = ash[m * 16 + quad * 4 + 0];
          float a1 = ash[m * 16 + quad * 4 + 1];
          float a2 = ash[m * 16 + quad * 4 + 2];
          float a3 = ash[m * 16 + quad * 4 + 3];
#pragma unroll
          for (int n = 0; n < 8; ++n) {
            o[m][n][0] *= a0; o[m][n][1] *= a1; o[m][n][2] *= a2; o[m][n][3] *= a3;
          }
        }
      }
      int4 pf[4];
#pragma unroll
      for (int m = 0; m < 4; ++m)
        pf[m] = *(int4*)&Psh[(m * 16 + r) * PST + quad * 8];
#pragma unroll
      for (int n = 0; n < 8; ++n) {
        const unsigned short* vp = &Vtsh[(wave * 128 + n * 16 + r) * VST + quad * 8];
        int4 vb = make_int4(*(const u32*)vp, *(const u32*)(vp + 2),
                            *(const u32*)(vp + 4), *(const u32*)(vp + 6));
#pragma unroll
        for (int m = 0; m < 4; ++m) o[m][n] = mfma16(pf[m], vb, o[m][n]);
      }
    }
  }

#pragma unroll
  for (int m = 0; m < 4; ++m) {
    float inv0 = 1.0f / lsh[m * 16 + quad * 4 + 0];
    float inv1 = 1.0f / lsh[m * 16 + quad * 4 + 1];
    float inv2 = 1.0f / lsh[m * 16 + quad * 4 + 2];
    float inv3 = 1.0f / lsh[m * 16 + quad * 4 + 3];
#pragma unroll
    for (int n = 0; n < 8; ++n) {
      size_t row = (size_t)q0 + m * 16 + quad * 4;
      size_t col = (size_t)wave * 128 + n * 16 + r;
      Ob[(row + 0) * D_DIM + col] = o[m][n][0] * inv0;
      Ob[(row + 1) * D_DIM + col] = o[m][n][1] * inv1;
      Ob[(row + 2) * D_DIM + col] = o[m][n][2] * inv2;
      Ob[(row + 3) * D_DIM + col] = o[m][n][3] * inv3;
    }
  }
}

extern "C" void kernel_launch(void* const* d_in, const int* in_sizes, int n_in,
                              void* d_out, int out_size, void* d_ws, size_t ws_size,
                              hipStream_t stream) {
  const float* Q = (const float*)d_in[0];
  const float* K = (const float*)d_in[1];
  const float* V = (const float*)d_in[2];
  float* O = (float*)d_out;
  int B = in_sizes[0] / (L_SEQ * D_DIM);

  size_t need = (size_t)B * L_SEQ * D_DIM * 2ull * 2ull;  // Kb16 + Vt (bf16)
  if (d_ws != nullptr && ws_size >= need) {
    unsigned short* Kb16 = (unsigned short*)d_ws;
    unsigned short* Vt = Kb16 + (size_t)B * L_SEQ * D_DIM;
    dim3 g1(NKT, B);
    cvt_kv<<<g1, 512, 0, stream>>>(K, V, Kb16, Vt);
    dim3 g2(L_SEQ / BQ, B);
    fa_fwd_pre<<<g2, NTHREADS, 0, stream>>>(Q, Kb16, Vt, O, B);
  } else {
    (void)hipFuncSetAttribute((const void*)fa_fwd, hipFuncAttributeMaxDynamicSharedMemorySize,
                              LDS_TOTAL);
    dim3 grid(L_SEQ / BQ, B);
    fa_fwd<<<grid, NTHREADS, LDS_TOTAL, stream>>>(Q, K, V, O);
  }
}

// Round 5
// 725.217 us; speedup vs baseline: 1.7986x; 1.7986x over previous
//
#include <hip/hip_runtime.h>
#include <cstdint>

#define NTHREADS 512
#define L_SEQ 2048
#define D_DIM 1024
#define BQ 64
#define BK 32
#define NKT (L_SEQ / BK)   // 64 key tiles
#define NQT (L_SEQ / BQ)   // 32 query tiles

// ---- fallback (original) kernel LDS layout ----
#define KST 1032
#define VST 34
#define SST 36
#define PST 40
#define K_OFF 0
#define K_BYTES (BK * KST * 2)
#define V_OFF (K_OFF + K_BYTES)
#define V_BYTES (D_DIM * VST * 2)
#define S_OFF (V_OFF + V_BYTES)
#define S_BYTES (BQ * SST * 4)
#define P_OFF (S_OFF + S_BYTES)
#define P_BYTES (BQ * PST * 2)
#define M_OFF (P_OFF + P_BYTES)
#define LDS_TOTAL (M_OFF + BQ * 4 * 3 + 16)

typedef unsigned int u32;
typedef __bf16 bf16x8 __attribute__((ext_vector_type(8)));
typedef float f32x4 __attribute__((ext_vector_type(4)));

// nt-load helper: __builtin_nontemporal_load rejects HIP_vector_type pointers,
// but accepts clang ext_vector_type.
__device__ __forceinline__ f32x4 ntload4(const float* p) {
  return __builtin_nontemporal_load((const f32x4*)p);
}

__device__ __forceinline__ f32x4 mfma16(int4 a, int4 b, f32x4 c) {
  return __builtin_amdgcn_mfma_f32_16x16x32_bf16(
      __builtin_bit_cast(bf16x8, a), __builtin_bit_cast(bf16x8, b), c, 0, 0, 0);
}

// pack two fp32 -> bf16x2 (same rounding as previous verified kernel)
__device__ __forceinline__ u32 pk2(float a, float b) {
  u32 ua = __float_as_uint(a) + 0x8000u;
  u32 ub = __float_as_uint(b) + 0x8000u;
  return (ua >> 16) | (ub & 0xffff0000u);
}

#define SFIX 4096.0f

// ================= prologue: K -> bf16 (same layout), V -> bf16 tile-transposed =================
// Vt layout: [b][kt][d][32 keys] bf16, each tile a contiguous 64KB chunk.
// All 16 V float4 preloaded to regs BEFORE the barrier-separated chunk phases.
#define CVT_PAD 257   // 257 % 32 == 1 -> transpose-gather reads are 2-way (free)

__global__ __launch_bounds__(512)
void cvt_kv(const float* __restrict__ Kg, const float* __restrict__ Vg,
            unsigned short* __restrict__ Kb16, unsigned short* __restrict__ Vt) {
  __shared__ float vls[32 * CVT_PAD];   // 32.9 KB
  const int tid = threadIdx.x;
  const int kt = blockIdx.x;
  const int b = blockIdx.y;
  const size_t inbase = ((size_t)b * L_SEQ + (size_t)kt * BK) * D_DIM;

  // K tile convert: 32x1024 fp32 -> bf16, flat coalesced, nt reads
  {
    const float* Ks = Kg + inbase;
    uint2* Ko = (uint2*)(Kb16 + inbase);
#pragma unroll
    for (int i = 0; i < 16; ++i) {
      f32x4 x = ntload4(Ks + (size_t)(i * 512 + tid) * 4);
      Ko[i * 512 + tid] = make_uint2(pk2(x[0], x[1]), pk2(x[2], x[3]));
    }
  }
  // V: preload ALL chunks into registers (16 f32x4), then barriered transpose phases
  const float* Vsf = Vg + inbase;
  f32x4 vr[16];
#pragma unroll
  for (int i = 0; i < 16; ++i) {
    int u = (i & 3) * 512 + tid;       // within-chunk flat index
    int c = i >> 2;                     // chunk 0..3
    int row = u >> 6;                   // key 0..31
    int col4 = u & 63;                  // float4 within 256-d chunk
    vr[i] = ntload4(Vsf + (size_t)row * D_DIM + c * 256 + col4 * 4);
  }
  int4* Vo = (int4*)(Vt + ((size_t)b * NKT + kt) * (size_t)(D_DIM * BK));
#pragma unroll
  for (int c = 0; c < 4; ++c) {
    __syncthreads();   // previous chunk's readers done
#pragma unroll
    for (int i = 0; i < 4; ++i) {
      int u = i * 512 + tid;
      int row = u >> 6;
      int col4 = u & 63;
      *(f32x4*)&vls[row * CVT_PAD + col4 * 4] = vr[c * 4 + i];
    }
    __syncthreads();
#pragma unroll
    for (int i = 0; i < 2; ++i) {
      int o4 = i * 512 + tid;          // 0..1023
      int d = o4 >> 2;                 // 0..255 (chunk-local)
      int k0 = (o4 & 3) * 8;           // key start for this int4 (8 keys)
      u32 w0 = pk2(vls[(k0 + 0) * CVT_PAD + d], vls[(k0 + 1) * CVT_PAD + d]);
      u32 w1 = pk2(vls[(k0 + 2) * CVT_PAD + d], vls[(k0 + 3) * CVT_PAD + d]);
      u32 w2 = pk2(vls[(k0 + 4) * CVT_PAD + d], vls[(k0 + 5) * CVT_PAD + d]);
      u32 w3 = pk2(vls[(k0 + 6) * CVT_PAD + d], vls[(k0 + 7) * CVT_PAD + d]);
      Vo[(c * 256 + d) * 4 + (o4 & 3)] = make_int4((int)w0, (int)w1, (int)w2, (int)w3);
    }
  }
}

// ================= main kernel: R3 structure + defer-max + 4-fragment V prefetch =================
__global__ __attribute__((amdgpu_waves_per_eu(2, 2))) __launch_bounds__(NTHREADS)
void fa_fwd_pre(const float* __restrict__ Qg, const unsigned short* __restrict__ Kb16,
                const unsigned short* __restrict__ Vt, float* __restrict__ Og, int B) {
  __shared__ int Ssh[BQ * SST];                 // fixed-point partial scores
  __shared__ unsigned short Psh[BQ * PST];      // bf16 probs
  __shared__ float msh[BQ], lsh[BQ], ash[BQ];   // running max / denom / alpha
  __shared__ int fsh[2][4];                     // double-buffered rescale flags

  const int tid = threadIdx.x;
  const int lane = tid & 63;
  const int wave = tid >> 6;         // d-slice owner: cols [wave*128, wave*128+128)
  const int r = lane & 15;
  const int quad = lane >> 4;

  // XCD-co-scheduled mapping: all 32 CUs of an XCD stream one batch's K/V window.
  const int f = (int)blockIdx.y * (int)gridDim.x + (int)blockIdx.x;
  int b, qtile;
  if ((B & 7) == 0) {
    int xcd = f & 7;
    int s = f >> 3;                   // per-XCD slot
    b = (s >> 5) * 8 + xcd;          // round * 8 + xcd   (NQT == 32)
    qtile = (NQT - 1) - (s & (NQT - 1));
  } else {
    b = f % B;
    qtile = (int)gridDim.x - 1 - (f / B);
  }
  const int q0 = qtile * BQ;
  const size_t base = (size_t)b * L_SEQ * D_DIM;
  const float* Qb = Qg + base;
  const unsigned short* Kbb = Kb16 + base;
  const unsigned short* Vtb = Vt + (size_t)b * NKT * (size_t)(D_DIM * BK);
  float* Ob = Og + base;

  // ---- Q fragments, bf16, persistent (nt loads: Q touched exactly once) ----
  int4 qf[4][4];
#pragma unroll
  for (int m = 0; m < 4; ++m)
#pragma unroll
    for (int ks = 0; ks < 4; ++ks) {
      const float* src = Qb + (size_t)(q0 + m * 16 + r) * D_DIM + wave * 128 + ks * 32 + quad * 8;
      f32x4 x = ntload4(src);
      f32x4 y = ntload4(src + 4);
      qf[m][ks] = make_int4((int)pk2(x[0], x[1]), (int)pk2(x[2], x[3]),
                            (int)pk2(y[0], y[1]), (int)pk2(y[2], y[3]));
    }

  f32x4 o[4][8];
  const f32x4 fzero = {0.f, 0.f, 0.f, 0.f};
#pragma unroll
  for (int m = 0; m < 4; ++m)
#pragma unroll
    for (int n = 0; n < 8; ++n) o[m][n] = fzero;

  if (tid < BQ) { msh[tid] = -3.0e38f; lsh[tid] = 0.f; }
  if (tid < 8) fsh[tid >> 2][tid & 3] = 0;
  {  // zero score buffer once; thereafter softmax re-zeros its own int4
    int q = tid >> 3, k4 = (tid & 7) * 4;
    *(int4*)&Ssh[q * SST + k4] = make_int4(0, 0, 0, 0);
  }
  __syncthreads();

  const int nkt = q0 / BK + 2;                 // causal tile skip
  const float SC = 0.04508422002778011f;       // log2(e) / sqrt(1024)
  const float SCI = SC / SFIX;

  for (int kt = 0; kt < nkt; ++kt) {
    const int cur = kt & 1;
    const unsigned short* Vtt = Vtb + (size_t)kt * (D_DIM * BK);

    // ---- V prefetch, 4 of 8 fragments (+16 VGPR): latency hides under QK^T+softmax ----
    int4 vpre[4];
#pragma unroll
    for (int n = 0; n < 4; ++n)
      vpre[n] = *(const int4*)(Vtt + (wave * 128 + n * 16 + r) * BK + quad * 8);

    // ---- QK^T: direct global bf16 K fragments, reduce via LDS int atomics ----
#pragma unroll
    for (int nb = 0; nb < 2; ++nb) {
      f32x4 sp[4];
#pragma unroll
      for (int m = 0; m < 4; ++m) sp[m] = fzero;
#pragma unroll
      for (int ks = 0; ks < 4; ++ks) {
        int4 kb = *(const int4*)(Kbb + (size_t)(kt * BK + nb * 16 + r) * D_DIM +
                                 wave * 128 + ks * 32 + quad * 8);
#pragma unroll
        for (int m = 0; m < 4; ++m) sp[m] = mfma16(qf[m][ks], kb, sp[m]);
      }
#pragma unroll
      for (int m = 0; m < 4; ++m)
#pragma unroll
        for (int i = 0; i < 4; ++i) {
          int v = __float2int_rn(sp[m][i] * SFIX);
          atomicAdd(&Ssh[(m * 16 + quad * 4 + i) * SST + nb * 16 + r], v);
        }
    }
    __syncthreads();  // (1) S complete; prev-tile P/ash consumers also done

    // ---- online softmax with defer-max (T13): rescale only when max grows >8 ----
    {
      int q = tid >> 3, kk = (tid & 7) * 4;
      int4 sv = *(int4*)&Ssh[q * SST + kk];
      *(int4*)&Ssh[q * SST + kk] = make_int4(0, 0, 0, 0);
      int qglob = q0 + q, kglob = kt * BK + kk;
      float e0 = (kglob <= qglob) ? (float)sv.x * SCI : -1e30f;
      float e1 = (kglob + 1 <= qglob) ? (float)sv.y * SCI : -1e30f;
      float e2 = (kglob + 2 <= qglob) ? (float)sv.z * SCI : -1e30f;
      float e3 = (kglob + 3 <= qglob) ? (float)sv.w * SCI : -1e30f;
      float mx = fmaxf(fmaxf(e0, e1), fmaxf(e2, e3));
      mx = fmaxf(mx, __shfl_xor(mx, 1));
      mx = fmaxf(mx, __shfl_xor(mx, 2));
      mx = fmaxf(mx, __shfl_xor(mx, 4));
      float mprev = msh[q], lprev = lsh[q];
      // defer-max: P bounded by 2^8=256 (f32 accum + bf16 rel-error unchanged)
      bool resc = (mx - mprev) > 8.0f;
      float mused = resc ? mx : mprev;
      float alpha = resc ? exp2f(mprev - mx) : 1.0f;
      float p0 = exp2f(e0 - mused), p1 = exp2f(e1 - mused);
      float p2 = exp2f(e2 - mused), p3 = exp2f(e3 - mused);
      float sum = (p0 + p1) + (p2 + p3);
      sum += __shfl_xor(sum, 1);
      sum += __shfl_xor(sum, 2);
      sum += __shfl_xor(sum, 4);
      *(uint2*)&Psh[q * PST + kk] = make_uint2(pk2(p0, p1), pk2(p2, p3));
      if ((tid & 7) == 0) {
        msh[q] = mused;
        lsh[q] = lprev * alpha + sum;
        ash[q] = alpha;
        if (resc) fsh[cur][q >> 4] = 1;  // same-value racy store: fine
      }
      if (tid < 4) fsh[cur ^ 1][tid] = 0;          // reset next tile's flags
    }
    __syncthreads();  // (2) P/alpha/flags ready

    // ---- rare O rescale + PV (vpre 0..3, early-issued loads 4..7) ----
    {
      int4 vb2[4];
#pragma unroll
      for (int n = 4; n < 8; ++n)   // issue remaining V loads before MFMAs
        vb2[n - 4] = *(const int4*)(Vtt + (wave * 128 + n * 16 + r) * BK + quad * 8);
#pragma unroll
      for (int m = 0; m < 4; ++m) {
        if (fsh[cur][m]) {  // wave-uniform; rare with defer-max
          float a0 = ash[m * 16 + quad * 4 + 0];
          float a1 = ash[m * 16 + quad * 4 + 1];
          float a2 = ash[m * 16 + quad * 4 + 2];
          float a3 = ash[m * 16 + quad * 4 + 3];
#pragma unroll
          for (int n = 0; n < 8; ++n) {
            o[m][n][0] *= a0; o[m][n][1] *= a1; o[m][n][2] *= a2; o[m][n][3] *= a3;
          }
        }
      }
      int4 pf[4];
#pragma unroll
      for (int m = 0; m < 4; ++m)
        pf[m] = *(int4*)&Psh[(m * 16 + r) * PST + quad * 8];
#pragma unroll
      for (int n = 0; n < 4; ++n) {
#pragma unroll
        for (int m = 0; m < 4; ++m) o[m][n] = mfma16(pf[m], vpre[n], o[m][n]);
      }
#pragma unroll
      for (int n = 4; n < 8; ++n) {
#pragma unroll
        for (int m = 0; m < 4; ++m) o[m][n] = mfma16(pf[m], vb2[n - 4], o[m][n]);
      }
    }
  }

  // ---- epilogue: O / l (nt stores: O never re-read) ----
#pragma unroll
  for (int m = 0; m < 4; ++m) {
    float inv0 = 1.0f / lsh[m * 16 + quad * 4 + 0];
    float inv1 = 1.0f / lsh[m * 16 + quad * 4 + 1];
    float inv2 = 1.0f / lsh[m * 16 + quad * 4 + 2];
    float inv3 = 1.0f / lsh[m * 16 + quad * 4 + 3];
#pragma unroll
    for (int n = 0; n < 8; ++n) {
      size_t row = (size_t)q0 + m * 16 + quad * 4;
      size_t col = (size_t)wave * 128 + n * 16 + r;
      __builtin_nontemporal_store(o[m][n][0] * inv0, &Ob[(row + 0) * D_DIM + col]);
      __builtin_nontemporal_store(o[m][n][1] * inv1, &Ob[(row + 1) * D_DIM + col]);
      __builtin_nontemporal_store(o[m][n][2] * inv2, &Ob[(row + 2) * D_DIM + col]);
      __builtin_nontemporal_store(o[m][n][3] * inv3, &Ob[(row + 3) * D_DIM + col]);
    }
  }
}

// ================= fallback: previous verified kernel (used if workspace too small) =================
__global__ __attribute__((amdgpu_waves_per_eu(2, 2))) __launch_bounds__(NTHREADS)
void fa_fwd(const float* __restrict__ Qg, const float* __restrict__ Kg,
            const float* __restrict__ Vg, float* __restrict__ Og) {
  extern __shared__ char smem[];
  unsigned short* Ksh = (unsigned short*)(smem + K_OFF);
  unsigned short* Vtsh = (unsigned short*)(smem + V_OFF);
  int* Ssh = (int*)(smem + S_OFF);
  unsigned short* Psh = (unsigned short*)(smem + P_OFF);
  float* msh = (float*)(smem + M_OFF);
  float* lsh = msh + BQ;
  float* ash = lsh + BQ;
  int* fsh = (int*)(ash + BQ);

  const int tid = threadIdx.x;
  const int lane = tid & 63;
  const int wave = tid >> 6;
  const int r = lane & 15;
  const int quad = lane >> 4;

  const int qtile = (int)gridDim.x - 1 - (int)blockIdx.x;
  const int q0 = qtile * BQ;
  const int b = blockIdx.y;
  const size_t base = (size_t)b * L_SEQ * D_DIM;
  const float* Qb = Qg + base;
  const float* Kb = Kg + base;
  const float* Vb = Vg + base;
  float* Ob = Og + base;

  int4 qf[4][4];
#pragma unroll
  for (int m = 0; m < 4; ++m)
#pragma unroll
    for (int ks = 0; ks < 4; ++ks) {
      const float* src = Qb + (size_t)(q0 + m * 16 + r) * D_DIM + wave * 128 + ks * 32 + quad * 8;
      float4 x = *(const float4*)src;
      float4 y = *(const float4*)(src + 4);
      qf[m][ks] = make_int4((int)pk2(x.x, x.y), (int)pk2(x.z, x.w),
                            (int)pk2(y.x, y.y), (int)pk2(y.z, y.w));
    }

  f32x4 o[4][8];
  const f32x4 fzero = {0.f, 0.f, 0.f, 0.f};
#pragma unroll
  for (int m = 0; m < 4; ++m)
#pragma unroll
    for (int n = 0; n < 8; ++n) o[m][n] = fzero;

  if (tid < BQ) { msh[tid] = -3.0e38f; lsh[tid] = 0.f; }

  const int nkt = q0 / BK + 2;
  const float SC = 0.04508422002778011f;
  const float SCI = SC / SFIX;

  for (int kt = 0; kt < nkt; ++kt) {
    __syncthreads();
    {
      const float* Ks = Kb + (size_t)kt * BK * D_DIM;
#pragma unroll 8
      for (int i = 0; i < 16; ++i) {
        int u = i * NTHREADS + tid;
        int key = u >> 8;
        int c = u & 255;
        float4 v = *(const float4*)(Ks + key * D_DIM + c * 4);
        *(uint2*)&Ksh[key * KST + c * 4] = make_uint2(pk2(v.x, v.y), pk2(v.z, v.w));
      }
      const float* Vs = Vb + (size_t)kt * BK * D_DIM;
#pragma unroll 8
      for (int i = 0; i < 32; ++i) {
        int u = i * NTHREADS + tid;
        int kp = u >> 10;
        int d = u & 1023;
        float a = Vs[kp * 2 * D_DIM + d];
        float c2 = Vs[(kp * 2 + 1) * D_DIM + d];
        *(u32*)&Vtsh[d * VST + kp * 2] = pk2(a, c2);
      }
      int q = tid >> 3, k4 = (tid & 7) * 4;
      *(int4*)&Ssh[q * SST + k4] = make_int4(0, 0, 0, 0);
      if (tid < 4) fsh[tid] = 0;
    }
    __syncthreads();

#pragma unroll
    for (int nb = 0; nb < 2; ++nb) {
      f32x4 sp[4];
#pragma unroll
      for (int m = 0; m < 4; ++m) sp[m] = fzero;
#pragma unroll
      for (int ks = 0; ks < 4; ++ks) {
        int dcol = wave * 128 + ks * 32 + quad * 8;
        int4 kb = *(int4*)&Ksh[(nb * 16 + r) * KST + dcol];
#pragma unroll
        for (int m = 0; m < 4; ++m) sp[m] = mfma16(qf[m][ks], kb, sp[m]);
      }
#pragma unroll
      for (int m = 0; m < 4; ++m)
#pragma unroll
        for (int i = 0; i < 4; ++i) {
          int v = __float2int_rn(sp[m][i] * SFIX);
          atomicAdd(&Ssh[(m * 16 + quad * 4 + i) * SST + nb * 16 + r], v);
        }
    }
    __syncthreads();

    {
      int q = tid >> 3, kk = (tid & 7) * 4;
      int4 sv = *(int4*)&Ssh[q * SST + kk];
      int qglob = q0 + q, kglob = kt * BK + kk;
      float e0 = (kglob <= qglob) ? (float)sv.x * SCI : -1e30f;
      float e1 = (kglob + 1 <= qglob) ? (float)sv.y * SCI : -1e30f;
      float e2 = (kglob + 2 <= qglob) ? (float)sv.z * SCI : -1e30f;
      float e3 = (kglob + 3 <= qglob) ? (float)sv.w * SCI : -1e30f;
      float mx = fmaxf(fmaxf(e0, e1), fmaxf(e2, e3));
      mx = fmaxf(mx, __shfl_xor(mx, 1));
      mx = fmaxf(mx, __shfl_xor(mx, 2));
      mx = fmaxf(mx, __shfl_xor(mx, 4));
      float mprev = msh[q], lprev = lsh[q];
      float mnew = fmaxf(mprev, mx);
      float alpha = exp2f(mprev - mnew);
      float p0 = exp2f(e0 - mnew), p1 = exp2f(e1 - mnew);
      float p2 = exp2f(e2 - mnew), p3 = exp2f(e3 - mnew);
      float sum = (p0 + p1) + (p2 + p3);
      sum += __shfl_xor(sum, 1);
      sum += __shfl_xor(sum, 2);
      sum += __shfl_xor(sum, 4);
      *(uint2*)&Psh[q * PST + kk] = make_uint2(pk2(p0, p1), pk2(p2, p3));
      if ((tid & 7) == 0) {
        msh[q] = mnew;
        lsh[q] = lprev * alpha + sum;
        ash[q] = alpha;
        if (alpha != 1.0f) fsh[q >> 4] = 1;
      }
    }
    __syncthreads();

    {
#pragma unroll
      for (int m = 0; m < 4; ++m) {
        if (fsh[m]) {
          float a0 = ash[m * 16 + quad * 4 + 0];
          float a1 = ash[m * 16 + quad * 4 + 1];
          float a2 = ash[m * 16 + quad * 4 + 2];
          float a3 = ash[m * 16 + quad * 4 + 3];
#pragma unroll
          for (int n = 0; n < 8; ++n) {
            o[m][n][0] *= a0; o[m][n][1] *= a1; o[m][n][2] *= a2; o[m][n][3] *= a3;
          }
        }
      }
      int4 pf[4];
#pragma unroll
      for (int m = 0; m < 4; ++m)
        pf[m] = *(int4*)&Psh[(m * 16 + r) * PST + quad * 8];
#pragma unroll
      for (int n = 0; n < 8; ++n) {
        const unsigned short* vp = &Vtsh[(wave * 128 + n * 16 + r) * VST + quad * 8];
        int4 vb = make_int4(*(const u32*)vp, *(const u32*)(vp + 2),
                            *(const u32*)(vp + 4), *(const u32*)(vp + 6));
#pragma unroll
        for (int m = 0; m < 4; ++m) o[m][n] = mfma16(pf[m], vb, o[m][n]);
      }
    }
  }

#pragma unroll
  for (int m = 0; m < 4; ++m) {
    float inv0 = 1.0f / lsh[m * 16 + quad * 4 + 0];
    float inv1 = 1.0f / lsh[m * 16 + quad * 4 + 1];
    float inv2 = 1.0f / lsh[m * 16 + quad * 4 + 2];
    float inv3 = 1.0f / lsh[m * 16 + quad * 4 + 3];
#pragma unroll
    for (int n = 0; n < 8; ++n) {
      size_t row = (size_t)q0 + m * 16 + quad * 4;
      size_t col = (size_t)wave * 128 + n * 16 + r;
      Ob[(row + 0) * D_DIM + col] = o[m][n][0] * inv0;
      Ob[(row + 1) * D_DIM + col] = o[m][n][1] * inv1;
      Ob[(row + 2) * D_DIM + col] = o[m][n][2] * inv2;
      Ob[(row + 3) * D_DIM + col] = o[m][n][3] * inv3;
    }
  }
}

extern "C" void kernel_launch(void* const* d_in, const int* in_sizes, int n_in,
                              void* d_out, int out_size, void* d_ws, size_t ws_size,
                              hipStream_t stream) {
  const float* Q = (const float*)d_in[0];
  const float* K = (const float*)d_in[1];
  const float* V = (const float*)d_in[2];
  float* O = (float*)d_out;
  int B = in_sizes[0] / (L_SEQ * D_DIM);

  size_t need = (size_t)B * L_SEQ * D_DIM * 2ull * 2ull;  // Kb16 + Vt (bf16)
  if (d_ws != nullptr && ws_size >= need) {
    unsigned short* Kb16 = (unsigned short*)d_ws;
    unsigned short* Vt = Kb16 + (size_t)B * L_SEQ * D_DIM;
    dim3 g1(NKT, B);
    cvt_kv<<<g1, 512, 0, stream>>>(K, V, Kb16, Vt);
    dim3 g2(L_SEQ / BQ, B);
    fa_fwd_pre<<<g2, NTHREADS, 0, stream>>>(Q, Kb16, Vt, O, B);
  } else {
    (void)hipFuncSetAttribute((const void*)fa_fwd, hipFuncAttributeMaxDynamicSharedMemorySize,
                              LDS_TOTAL);
    dim3 grid(L_SEQ / BQ, B);
    fa_fwd<<<grid, NTHREADS, LDS_TOTAL, stream>>>(Q, K, V, O);
  }
}